// Round 17
// baseline (252.684 us; speedup 1.0000x reference)
//
#include <hip/hip_runtime.h>
#include <stdint.h>

// ---------------------------------------------------------------------------
// EdgeNodeGCN on MI355X (gfx950). Inputs fp32, edge_index int32, output fp32.
// Factorization:
//   P[n]  = x[n] @ (Wa - Wb) + b_edge   (Wa = W_edge[0:128], Wb = W_edge[128:256])
//   Q[n]  = x[n] @ Wb
//   msg(e)= relu(P[dst] + Q[src]);  edge_agg[d] = sum msg
//   XA[d] = sum_{e->d} x[src]           (segment_sum commutes with @W_node)
//   nodes = relu(XA @ W_node + b_node); edges = relu(edge_agg @ W_ed + b_ed)
//   out   = sigmoid(relu([nodes|edges] @ W_f1 + b_f1) @ W_f2 + b_f2)
//
// R26 == R25 resubmit (R25 never ran: GPU acquisition timeout).
// R25 vs R24 (233.5, REGRESSION): grid 512->1563 did NOT raise occupancy
// (16.7->17.9%) -> residency pinned at ~2 blocks/CU by REGISTERS (128 VGPR +
// MFMA AGPRs, unified file), not grid. Fewer tiles/block tripled the
// per-block weight-prologue traffic (155KB/block: 79->242MB L2) = +16us.
// Revert grid to 512 (R23 = 217.6 best). Since occupancy is register-pinned,
// extra VGPRs are FREE -> 4-WAY UNROLL the gather edge loop (12x16B loads in
// flight/lane vs 6; R13's null doesn't apply because occ can't drop further).
// Plus xe stride 392->396 (read bank conflicts 8way->4way).
// Predicted: k_tailg 80 -> ~60-68us, hbm 2.1->~3 TB/s, Occ ~17% (unchanged,
// confirms pin), conflicts 1.2M -> <0.6M, total -> ~198-205.
// Dispatches: convert, sg, tailg (3).
// ---------------------------------------------------------------------------

typedef short short8 __attribute__((ext_vector_type(8)));
typedef float f32x4 __attribute__((ext_vector_type(4)));
typedef float float4v __attribute__((ext_vector_type(4)));
typedef unsigned short us8 __attribute__((ext_vector_type(8)));
typedef unsigned short us4 __attribute__((ext_vector_type(4)));

__device__ inline float bf2f(unsigned short h) {
    union { unsigned int u; float f; } v;
    v.u = ((unsigned int)h) << 16;
    return v.f;
}
__device__ inline unsigned short f2bf(float f) {
    union { float f; unsigned int u; } v;
    v.f = f;
    unsigned int r = v.u + 0x7FFFu + ((v.u >> 16) & 1u);  // RNE
    return (unsigned short)(r >> 16);
}

// ---- convert x + weights -> bf16 (coalesced writes); head/deg init --------
__global__ __launch_bounds__(256) void k_convert(
    const float* __restrict__ x, const float* __restrict__ W_edge,
    const float* __restrict__ W_node, const float* __restrict__ W_ed,
    const float* __restrict__ W_f1,
    unsigned short* __restrict__ xb, unsigned short* __restrict__ WE2T,
    unsigned short* __restrict__ WnT, unsigned short* __restrict__ WdT,
    unsigned short* __restrict__ Wf1P, int* __restrict__ head,
    int* __restrict__ deg,
    int quads, int N)
{
    int i = blockIdx.x * 256 + threadIdx.x;
    if (i < quads) {
        float4v v = ((const float4v*)x)[i];
        us4 o;
        for (int j = 0; j < 4; ++j) o[j] = f2bf(v[j]);
        ((us4*)xb)[i] = o;
        return;
    }
    int j = i - quads;
    if (j < 65536) {                          // WE2T [512 c][128 k]: write elem j
        int c = j >> 7, k = j & 127;
        float v;
        if (c < 256) v = W_edge[k * 256 + c] - W_edge[(k + 128) * 256 + c];
        else         v = W_edge[(k + 128) * 256 + (c - 256)];
        WE2T[j] = f2bf(v);
    } else if (j < 65536 + 32768) {           // WnT [256 c][128 k]
        int t = j - 65536;
        int c = t >> 7, k = t & 127;
        WnT[t] = f2bf(W_node[k * 256 + c]);
    } else if (j < 65536 + 65536) {           // WdT [128 c][256 k]
        int t = j - 65536 - 32768;
        int c = t >> 8, k = t & 255;
        WdT[t] = f2bf(W_ed[k * 128 + c]);
    } else if (j < 143360) {                  // Wf1P [32 c][384 kp] permuted
        int t = j - 65536 - 65536;
        int c = t / 384, kp = t - c * 384;
        int w = kp / 96, idx = kp % 96;
        int korig;
        if (idx < 64) korig = (w + (idx >> 4) * 4) * 16 + (idx & 15);
        else          korig = 256 + (w + ((idx - 64) >> 4) * 4) * 16 + (idx & 15);
        Wf1P[t] = f2bf(W_f1[korig * 32 + c]);
    } else {
        int t = j - 143360;
        if (t < N) { head[t] = -1; deg[t] = 0; }
    }
}

// ---- fused dispatch: padded-CSR build (1/3) + WIDE gemm (row-group/block) -
__global__ __launch_bounds__(512) void k_sg(
    const int* __restrict__ src, const int* __restrict__ dst,
    int* __restrict__ head, unsigned long long* __restrict__ next2,
    int* __restrict__ deg, int* __restrict__ adj,
    const unsigned short* __restrict__ xb,     // [N][128] bf16
    const unsigned short* __restrict__ WE2T,   // [512][128] bf16 col-major
    const float* __restrict__ b_edge,          // [256] fp32
    unsigned short* __restrict__ T,            // [N][512]
    int E, int N, int row_tiles, int scat_blocks, int gemm_blocks)
{
    __shared__ unsigned short st[2][16 * 524];
    int b = blockIdx.x;
    if (b % 3 == 2) {                          // scatter pass: padded CSR
        int sb_id = b / 3;
        if (sb_id >= scat_blocks) return;
        int i = sb_id * 512 + threadIdx.x;
        if (i >= E) return;
        int s = src[i], d = dst[i];
        if ((unsigned)d >= (unsigned)N || (unsigned)s >= (unsigned)N) return;
        int pos = atomicAdd(&deg[d], 1);
        if (pos < 32) {
            adj[(size_t)d * 32 + pos] = s;
        } else {                               // overflow: linked list
            int old = atomicExch(&head[d], i);
            next2[i] = ((unsigned long long)(unsigned)s << 32) | (unsigned)old;
        }
        return;
    }
    int g = b - b / 3;                         // gemm row-group id
    if (g >= gemm_blocks) return;

    const int lane = threadIdx.x & 63;
    const int wave = threadIdx.x >> 6;         // 0..7, owns cols [wave*64,+64)
    const int quad = lane >> 4;
    const int col16 = lane & 15;
    const int tid = threadIdx.x;

    // persistent B fragments: 4 col-chunks x 4 k-steps = 64 VGPR
    short8 bf[4][4];
    float bias[4];
#pragma unroll
    for (int cc = 0; cc < 4; ++cc) {
        int col = wave * 64 + cc * 16 + col16;
        bias[cc] = (col < 256) ? b_edge[col] : 0.f;
#pragma unroll
        for (int ks = 0; ks < 4; ++ks)
            bf[cc][ks] = *(const short8*)(WE2T + (size_t)col * 128 + ks * 32 + quad * 8);
    }

    int tmax = row_tiles - g * 8;              // block-uniform
    if (tmax > 8) tmax = 8;

    for (int t = 0; t < 8; ++t) {
        if (t >= tmax) break;                  // uniform: safe with barriers
        int r0 = (g * 8 + t) * 16;
        int arow = r0 + col16;
        if (arow >= N) arow = N - 1;

        // A-fragment: 4 loads feed 16 MFMAs
        short8 a[4];
        const unsigned short* ap = xb + (size_t)arow * 128 + quad * 8;
#pragma unroll
        for (int ks = 0; ks < 4; ++ks) a[ks] = *(const short8*)(ap + ks * 32);

        unsigned short* sbuf = st[t & 1];
#pragma unroll
        for (int cc = 0; cc < 4; ++cc) {
            f32x4 acc = {0.f, 0.f, 0.f, 0.f};
#pragma unroll
            for (int ks = 0; ks < 4; ++ks)
                acc = __builtin_amdgcn_mfma_f32_16x16x32_bf16(a[ks], bf[cc][ks], acc, 0, 0, 0);
#pragma unroll
            for (int r = 0; r < 4; ++r)
                sbuf[(quad * 4 + r) * 524 + wave * 64 + cc * 16 + col16] =
                    f2bf(acc[r] + bias[cc]);
        }

        __syncthreads();                       // one barrier per tile

        // store tile: 1024 us8-chunks, 512 threads x 2
#pragma unroll
        for (int p = 0; p < 2; ++p) {
            int chunk = tid + p * 512;
            int row = chunk >> 6;              // 0..15
            int cpos = (chunk & 63) * 8;       // 0..504
            if (r0 + row < N) {
                us8 v = *(const us8*)(sbuf + row * 524 + cpos);
                *(us8*)(T + (size_t)(r0 + row) * 512 + cpos) = v;
            }
        }
    }
}

// ---- Fused gather + tail: quarter-wave gather -> LDS -> MFMA --------------
__global__ __launch_bounds__(256, 2) void k_tailg(
    const unsigned short* __restrict__ T,    // [N][512] P|Q (read-only)
    const unsigned short* __restrict__ xb,   // [N][128]
    const int* __restrict__ deg,
    const int* __restrict__ adj,             // [N][32]
    const int* __restrict__ head,
    const unsigned long long* __restrict__ next2,
    const unsigned short* __restrict__ WnT,  // [256 c][128 k] col-major
    const unsigned short* __restrict__ WdT,  // [128 c][256 k] col-major
    const unsigned short* __restrict__ Wf1P, // [32 c][384 kp] permuted
    const float* __restrict__ b_node, const float* __restrict__ b_ed,
    const float* __restrict__ b_f1, const float* __restrict__ W_f2,
    const float* __restrict__ b_f2,
    float* __restrict__ out, int N, int row_tiles, int tiles_per_block)
{
    __shared__ unsigned short hslice[4][16 * 100];  // per-wave h (bf16)
    __shared__ float red[4][16][33];                // MLP partials
    __shared__ unsigned short xe[16 * 396];         // XA|EA per tile (pad 396)
    const int wave = threadIdx.x >> 6;
    const int lane = threadIdx.x & 63;
    const int quad = lane >> 4;
    const int col16 = lane & 15;

    // ---- persistent B fragments (loaded once per block) ----
    short8 bn[4][4], be[2][8], bfr[2][3];
    float bias_n[4], bias_e[2];
#pragma unroll
    for (int ci = 0; ci < 4; ++ci) {
        int col = (wave + ci * 4) * 16 + col16;
        bias_n[ci] = b_node[col];
#pragma unroll
        for (int ks = 0; ks < 4; ++ks)
            bn[ci][ks] = *(const short8*)(WnT + (size_t)col * 128 + ks * 32 + quad * 8);
    }
#pragma unroll
    for (int ci = 0; ci < 2; ++ci) {
        int col = (wave + ci * 4) * 16 + col16;
        bias_e[ci] = b_ed[col];
#pragma unroll
        for (int ks = 0; ks < 8; ++ks)
            be[ci][ks] = *(const short8*)(WdT + (size_t)col * 256 + ks * 32 + quad * 8);
    }
#pragma unroll
    for (int cc = 0; cc < 2; ++cc) {
        int c = cc * 16 + col16;
#pragma unroll
        for (int ks = 0; ks < 3; ++ks)
            bfr[cc][ks] = *(const short8*)(Wf1P + (size_t)c * 384 + wave * 96 + ks * 32 + quad * 8);
    }

    unsigned short* hw = &hslice[wave][0];
    int t0 = blockIdx.x * tiles_per_block;
    int t1 = t0 + tiles_per_block;
    if (t1 > row_tiles) t1 = row_tiles;

    for (int tile = t0; tile < t1; ++tile) {
        int r0 = tile * 16;

        // ================= gather phase: quarter-wave per node =============
        {
            int qn = wave * 4 + quad;            // node-in-tile 0..15
            int n = r0 + qn;
            bool act = n < N;
            int nn = act ? n : N - 1;
            int c = col16;

            // P row cols [c*16, c*16+16)
            us8 pv0 = *(const us8*)(T + (size_t)nn * 512 + c * 16);
            us8 pv1 = *(const us8*)(T + (size_t)nn * 512 + c * 16 + 8);
            float p[16];
#pragma unroll
            for (int j = 0; j < 8; ++j) { p[j] = bf2f(pv0[j]); p[j + 8] = bf2f(pv1[j]); }
            float aE[16];
#pragma unroll
            for (int j = 0; j < 16; ++j) aE[j] = 0.f;
            float aX[8] = {0, 0, 0, 0, 0, 0, 0, 0};

            int dg = act ? deg[n] : 0;
            int2 av = ((const int2*)(adj + (size_t)nn * 32))[c];  // slots 2c,2c+1
            int m = dg < 32 ? dg : 32;

            int k = 0;
            for (; k + 3 < m; k += 4) {          // 4-way unroll: 12x16B in flight
                int j0 = k >> 1, j1 = (k >> 1) + 1;
                int s0 = __shfl(av.x, j0, 16);
                int s1 = __shfl(av.y, j0, 16);
                int s2 = __shfl(av.x, j1, 16);
                int s3 = __shfl(av.y, j1, 16);
                us8 q0a = *(const us8*)(T + (size_t)s0 * 512 + 256 + c * 16);
                us8 q0b = *(const us8*)(T + (size_t)s0 * 512 + 256 + c * 16 + 8);
                us8 q1a = *(const us8*)(T + (size_t)s1 * 512 + 256 + c * 16);
                us8 q1b = *(const us8*)(T + (size_t)s1 * 512 + 256 + c * 16 + 8);
                us8 q2a = *(const us8*)(T + (size_t)s2 * 512 + 256 + c * 16);
                us8 q2b = *(const us8*)(T + (size_t)s2 * 512 + 256 + c * 16 + 8);
                us8 q3a = *(const us8*)(T + (size_t)s3 * 512 + 256 + c * 16);
                us8 q3b = *(const us8*)(T + (size_t)s3 * 512 + 256 + c * 16 + 8);
                us8 x0 = *(const us8*)(xb + (size_t)s0 * 128 + c * 8);
                us8 x1 = *(const us8*)(xb + (size_t)s1 * 128 + c * 8);
                us8 x2 = *(const us8*)(xb + (size_t)s2 * 128 + c * 8);
                us8 x3 = *(const us8*)(xb + (size_t)s3 * 128 + c * 8);
#pragma unroll
                for (int j = 0; j < 8; ++j) {
                    aE[j]     += fmaxf(p[j] + bf2f(q0a[j]), 0.f)
                               + fmaxf(p[j] + bf2f(q1a[j]), 0.f)
                               + fmaxf(p[j] + bf2f(q2a[j]), 0.f)
                               + fmaxf(p[j] + bf2f(q3a[j]), 0.f);
                    aE[j + 8] += fmaxf(p[j + 8] + bf2f(q0b[j]), 0.f)
                               + fmaxf(p[j + 8] + bf2f(q1b[j]), 0.f)
                               + fmaxf(p[j + 8] + bf2f(q2b[j]), 0.f)
                               + fmaxf(p[j + 8] + bf2f(q3b[j]), 0.f);
                    aX[j] += (bf2f(x0[j]) + bf2f(x1[j])) + (bf2f(x2[j]) + bf2f(x3[j]));
                }
            }
            for (; k < m; ++k) {                 // remainder 0..3
                int jj = k >> 1;
                int s0 = __shfl((k & 1) ? av.y : av.x, jj, 16);
                us8 q0a = *(const us8*)(T + (size_t)s0 * 512 + 256 + c * 16);
                us8 q0b = *(const us8*)(T + (size_t)s0 * 512 + 256 + c * 16 + 8);
                us8 x0 = *(const us8*)(xb + (size_t)s0 * 128 + c * 8);
#pragma unroll
                for (int j = 0; j < 8; ++j) {
                    aE[j]     += fmaxf(p[j] + bf2f(q0a[j]), 0.f);
                    aE[j + 8] += fmaxf(p[j + 8] + bf2f(q0b[j]), 0.f);
                    aX[j] += bf2f(x0[j]);
                }
            }

            // overflow fallback (deg > 32): residual linked list
            int cur = (act && dg > 32) ? head[n] : -1;
            while (__any(cur >= 0)) {
                bool v = cur >= 0;
                int safe = v ? cur : 0;
                unsigned long long e2 = next2[safe];
                int s = (int)(e2 >> 32);
                float mm = v ? 1.f : 0.f;
                us8 qa = *(const us8*)(T + (size_t)s * 512 + 256 + c * 16);
                us8 qb = *(const us8*)(T + (size_t)s * 512 + 256 + c * 16 + 8);
                us8 xv = *(const us8*)(xb + (size_t)s * 128 + c * 8);
#pragma unroll
                for (int j = 0; j < 8; ++j) {
                    aE[j]     += mm * fmaxf(p[j] + bf2f(qa[j]), 0.f);
                    aE[j + 8] += mm * fmaxf(p[j + 8] + bf2f(qb[j]), 0.f);
                    aX[j] += mm * bf2f(xv[j]);
                }
                cur = v ? (int)(unsigned)(e2 & 0xFFFFFFFFull) : -1;
            }

            // write to xe: row qn; XA cols [c*8,+8), EA cols 128+[c*16,+16)
            unsigned short* xr = xe + qn * 396;
            us8 xo;
#pragma unroll
            for (int j = 0; j < 8; ++j) xo[j] = f2bf(aX[j]);
            *(us8*)(xr + c * 8) = xo;
            us8 e0, e1;
#pragma unroll
            for (int j = 0; j < 8; ++j) { e0[j] = f2bf(aE[j]); e1[j] = f2bf(aE[j + 8]); }
            *(us8*)(xr + 128 + c * 16) = e0;
            *(us8*)(xr + 128 + c * 16 + 8) = e1;
        }
        __syncthreads();   // xe complete

        // ================= tail phase (A-fragments from xe) ================
        // --- node path: h[:,0:256], this wave's 4 chunks ---
        short8 ax[4];
#pragma unroll
        for (int ks = 0; ks < 4; ++ks)
            ax[ks] = *(const short8*)(xe + col16 * 396 + ks * 32 + quad * 8);
#pragma unroll
        for (int ci = 0; ci < 4; ++ci) {
            f32x4 acc = {0.f, 0.f, 0.f, 0.f};
#pragma unroll
            for (int ks = 0; ks < 4; ++ks)
                acc = __builtin_amdgcn_mfma_f32_16x16x32_bf16(ax[ks], bn[ci][ks], acc, 0, 0, 0);
#pragma unroll
            for (int r = 0; r < 4; ++r)
                hw[(quad * 4 + r) * 100 + ci * 16 + col16] =
                    f2bf(fmaxf(acc[r] + bias_n[ci], 0.f));
        }

        // --- edge path: h[:,256:384], this wave's 2 chunks ---
        short8 ae[8];
#pragma unroll
        for (int ks = 0; ks < 8; ++ks)
            ae[ks] = *(const short8*)(xe + col16 * 396 + 128 + ks * 32 + quad * 8);
#pragma unroll
        for (int ci = 0; ci < 2; ++ci) {
            f32x4 acc = {0.f, 0.f, 0.f, 0.f};
#pragma unroll
            for (int ks = 0; ks < 8; ++ks)
                acc = __builtin_amdgcn_mfma_f32_16x16x32_bf16(ae[ks], be[ci][ks], acc, 0, 0, 0);
#pragma unroll
            for (int r = 0; r < 4; ++r)
                hw[(quad * 4 + r) * 100 + 64 + ci * 16 + col16] =
                    f2bf(fmaxf(acc[r] + bias_e[ci], 0.f));
        }

        // --- MLP partial over own 96-K slice (same-wave LDS, no barrier) ---
        f32x4 m0 = {0.f, 0.f, 0.f, 0.f}, m1 = {0.f, 0.f, 0.f, 0.f};
#pragma unroll
        for (int ks = 0; ks < 3; ++ks) {
            short8 a = *(const short8*)(hw + col16 * 100 + ks * 32 + quad * 8);
            m0 = __builtin_amdgcn_mfma_f32_16x16x32_bf16(a, bfr[0][ks], m0, 0, 0, 0);
            m1 = __builtin_amdgcn_mfma_f32_16x16x32_bf16(a, bfr[1][ks], m1, 0, 0, 0);
        }
#pragma unroll
        for (int r = 0; r < 4; ++r) {
            red[wave][quad * 4 + r][col16] = m0[r];
            red[wave][quad * 4 + r][16 + col16] = m1[r];
        }
        __syncthreads();

        // --- final reduce + MLP2 + sigmoid on wave 0 ---
        if (wave == 0) {
            int row = col16, g = quad;          // each lane: 8 cols of one row
            float s = 0.f;
#pragma unroll
            for (int cc = 0; cc < 8; ++cc) {
                int col = g * 8 + cc;
                float v = red[0][row][col] + red[1][row][col] +
                          red[2][row][col] + red[3][row][col] + b_f1[col];
                s += fmaxf(v, 0.f) * W_f2[col];
            }
            s += __shfl_xor(s, 16, 64);
            s += __shfl_xor(s, 32, 64);
            if (g == 0 && r0 + row < N) {
                float v = s + b_f2[0];
                out[r0 + row] = 1.f / (1.f + __expf(-v));
            }
        }
        __syncthreads();   // red + xe reused next tile
    }
}

extern "C" void kernel_launch(void* const* d_in, const int* in_sizes, int n_in,
                              void* d_out, int out_size, void* d_ws, size_t ws_size,
                              hipStream_t stream) {
    const float* x      = (const float*)d_in[0];
    const int*   ei     = (const int*)d_in[1];
    // d_in[2] = e (unused)
    const float* W_node = (const float*)d_in[3];
    const float* b_node = (const float*)d_in[4];
    const float* W_edge = (const float*)d_in[5];
    const float* b_edge = (const float*)d_in[6];
    const float* W_ed   = (const float*)d_in[7];
    const float* b_ed   = (const float*)d_in[8];
    const float* W_f1   = (const float*)d_in[9];
    const float* b_f1   = (const float*)d_in[10];
    const float* W_f2   = (const float*)d_in[11];
    const float* b_f2   = (const float*)d_in[12];

    const int N = in_sizes[0] / 128;
    const int E = in_sizes[1] / 2;
    const int* src = ei;
    const int* dst = ei + E;

    char* ws = (char*)d_ws;
    size_t off = 0;
    auto alloc = [&](size_t bytes) { size_t o = off; off += (bytes + 255) & ~(size_t)255; return o; };
    unsigned short* xb   = (unsigned short*)(ws + alloc((size_t)N * 128 * 2));
    unsigned short* WE2T = (unsigned short*)(ws + alloc(512 * 128 * 2));
    unsigned short* WnT  = (unsigned short*)(ws + alloc(256 * 128 * 2));
    unsigned short* WdT  = (unsigned short*)(ws + alloc(128 * 256 * 2));
    unsigned short* Wf1P = (unsigned short*)(ws + alloc(32 * 384 * 2));
    unsigned short* T    = (unsigned short*)(ws + alloc((size_t)N * 512 * 2));
    int* head            = (int*)(ws + alloc((size_t)N * 4));
    unsigned long long* next2 = (unsigned long long*)(ws + alloc((size_t)E * 8));
    int* deg             = (int*)(ws + alloc((size_t)N * 4));
    int* adj             = (int*)(ws + alloc((size_t)N * 32 * 4));

    const int row_tiles   = (N + 15) / 16;
    const int row_groups  = (row_tiles + 7) / 8;
    const int quads       = N * 128 / 4;
    const int conv_items  = quads + 143360 + N;
    const int scat_blocks = (E + 511) / 512;
    const int gemm_blocks = row_groups;            // wide blocks: 1 per group
    int grid3 = scat_blocks * 3;
    int need_g = ((gemm_blocks + 1) / 2) * 3;
    if (need_g > grid3) grid3 = need_g;

    k_convert<<<(conv_items + 255) / 256, 256, 0, stream>>>(
        x, W_edge, W_node, W_ed, W_f1, xb, WE2T, WnT, WdT, Wf1P, head, deg,
        quads, N);
    k_sg<<<grid3, 512, 0, stream>>>(
        src, dst, head, next2, deg, adj, xb, WE2T, b_edge, T, E, N, row_tiles,
        scat_blocks, gemm_blocks);

    // 512 blocks: matches the ~2-block/CU register-pinned residency while
    // amortizing the per-block weight prologue over ~7 tiles (R24 lesson).
    int tail_blocks = 512;
    if (tail_blocks > row_tiles) tail_blocks = row_tiles;
    int tpb = (row_tiles + tail_blocks - 1) / tail_blocks;
    k_tailg<<<tail_blocks, 256, 0, stream>>>(
        T, xb, deg, adj, head, next2, WnT, WdT, Wf1P,
        b_node, b_ed, b_f1, W_f2, b_f2,
        (float*)d_out, N, row_tiles, tpb);
}

// Round 18
// 219.285 us; speedup vs baseline: 1.1523x; 1.1523x over previous
//
#include <hip/hip_runtime.h>
#include <stdint.h>

// ---------------------------------------------------------------------------
// EdgeNodeGCN on MI355X (gfx950). Inputs fp32, edge_index int32, output fp32.
// Factorization:
//   P[n]  = x[n] @ (Wa - Wb) + b_edge   (Wa = W_edge[0:128], Wb = W_edge[128:256])
//   Q[n]  = x[n] @ Wb
//   msg(e)= relu(P[dst] + Q[src]);  edge_agg[d] = sum msg
//   XA[d] = sum_{e->d} x[src]           (segment_sum commutes with @W_node)
//   nodes = relu(XA @ W_node + b_node); edges = relu(edge_agg @ W_ed + b_ed)
//   out   = sigmoid(relu([nodes|edges] @ W_f1 + b_f1) @ W_f2 + b_f2)
//
// R27 vs R26 (252.7, REGRESSION): 4-way unroll inflated FETCH 165->212MB
// (4 concurrent random 512B rows/quarter-wave thrash L2) at unchanged 2 TB/s
// -> k_tailg 80->117. Occ 16.7->17.5% re-confirms the register pin (152
// persistent weight VGPRs + accums ~256/wave -> 2 blocks/CU; VGPR_Count=128
// shows only the arch half). Stride 396 DID cut conflicts 1.2M->0.5M.
// REVERT to exact R23 (best, 217.6: 512 blocks, 2-way unroll) keeping only
// the stride-396 fix (LDS-only, orthogonal to the unroll regression).
// Predicted: k_tailg ~78-79, FETCH ~165MB, conflicts ~0.5M, total ~215-216.
// Next lever (documented, needs compile-probe VGPR check): 8-wave weight
// split to break the weights-vs-occupancy conflict.
// Dispatches: convert, sg, tailg (3).
// ---------------------------------------------------------------------------

typedef short short8 __attribute__((ext_vector_type(8)));
typedef float f32x4 __attribute__((ext_vector_type(4)));
typedef float float4v __attribute__((ext_vector_type(4)));
typedef unsigned short us8 __attribute__((ext_vector_type(8)));
typedef unsigned short us4 __attribute__((ext_vector_type(4)));

__device__ inline float bf2f(unsigned short h) {
    union { unsigned int u; float f; } v;
    v.u = ((unsigned int)h) << 16;
    return v.f;
}
__device__ inline unsigned short f2bf(float f) {
    union { float f; unsigned int u; } v;
    v.f = f;
    unsigned int r = v.u + 0x7FFFu + ((v.u >> 16) & 1u);  // RNE
    return (unsigned short)(r >> 16);
}

// ---- convert x + weights -> bf16 (coalesced writes); head/deg init --------
__global__ __launch_bounds__(256) void k_convert(
    const float* __restrict__ x, const float* __restrict__ W_edge,
    const float* __restrict__ W_node, const float* __restrict__ W_ed,
    const float* __restrict__ W_f1,
    unsigned short* __restrict__ xb, unsigned short* __restrict__ WE2T,
    unsigned short* __restrict__ WnT, unsigned short* __restrict__ WdT,
    unsigned short* __restrict__ Wf1P, int* __restrict__ head,
    int* __restrict__ deg,
    int quads, int N)
{
    int i = blockIdx.x * 256 + threadIdx.x;
    if (i < quads) {
        float4v v = ((const float4v*)x)[i];
        us4 o;
        for (int j = 0; j < 4; ++j) o[j] = f2bf(v[j]);
        ((us4*)xb)[i] = o;
        return;
    }
    int j = i - quads;
    if (j < 65536) {                          // WE2T [512 c][128 k]: write elem j
        int c = j >> 7, k = j & 127;
        float v;
        if (c < 256) v = W_edge[k * 256 + c] - W_edge[(k + 128) * 256 + c];
        else         v = W_edge[(k + 128) * 256 + (c - 256)];
        WE2T[j] = f2bf(v);
    } else if (j < 65536 + 32768) {           // WnT [256 c][128 k]
        int t = j - 65536;
        int c = t >> 7, k = t & 127;
        WnT[t] = f2bf(W_node[k * 256 + c]);
    } else if (j < 65536 + 65536) {           // WdT [128 c][256 k]
        int t = j - 65536 - 32768;
        int c = t >> 8, k = t & 255;
        WdT[t] = f2bf(W_ed[k * 128 + c]);
    } else if (j < 143360) {                  // Wf1P [32 c][384 kp] permuted
        int t = j - 65536 - 65536;
        int c = t / 384, kp = t - c * 384;
        int w = kp / 96, idx = kp % 96;
        int korig;
        if (idx < 64) korig = (w + (idx >> 4) * 4) * 16 + (idx & 15);
        else          korig = 256 + (w + ((idx - 64) >> 4) * 4) * 16 + (idx & 15);
        Wf1P[t] = f2bf(W_f1[korig * 32 + c]);
    } else {
        int t = j - 143360;
        if (t < N) { head[t] = -1; deg[t] = 0; }
    }
}

// ---- fused dispatch: padded-CSR build (1/3) + WIDE gemm (row-group/block) -
__global__ __launch_bounds__(512) void k_sg(
    const int* __restrict__ src, const int* __restrict__ dst,
    int* __restrict__ head, unsigned long long* __restrict__ next2,
    int* __restrict__ deg, int* __restrict__ adj,
    const unsigned short* __restrict__ xb,     // [N][128] bf16
    const unsigned short* __restrict__ WE2T,   // [512][128] bf16 col-major
    const float* __restrict__ b_edge,          // [256] fp32
    unsigned short* __restrict__ T,            // [N][512]
    int E, int N, int row_tiles, int scat_blocks, int gemm_blocks)
{
    __shared__ unsigned short st[2][16 * 524];
    int b = blockIdx.x;
    if (b % 3 == 2) {                          // scatter pass: padded CSR
        int sb_id = b / 3;
        if (sb_id >= scat_blocks) return;
        int i = sb_id * 512 + threadIdx.x;
        if (i >= E) return;
        int s = src[i], d = dst[i];
        if ((unsigned)d >= (unsigned)N || (unsigned)s >= (unsigned)N) return;
        int pos = atomicAdd(&deg[d], 1);
        if (pos < 32) {
            adj[(size_t)d * 32 + pos] = s;
        } else {                               // overflow: linked list
            int old = atomicExch(&head[d], i);
            next2[i] = ((unsigned long long)(unsigned)s << 32) | (unsigned)old;
        }
        return;
    }
    int g = b - b / 3;                         // gemm row-group id
    if (g >= gemm_blocks) return;

    const int lane = threadIdx.x & 63;
    const int wave = threadIdx.x >> 6;         // 0..7, owns cols [wave*64,+64)
    const int quad = lane >> 4;
    const int col16 = lane & 15;
    const int tid = threadIdx.x;

    // persistent B fragments: 4 col-chunks x 4 k-steps = 64 VGPR
    short8 bf[4][4];
    float bias[4];
#pragma unroll
    for (int cc = 0; cc < 4; ++cc) {
        int col = wave * 64 + cc * 16 + col16;
        bias[cc] = (col < 256) ? b_edge[col] : 0.f;
#pragma unroll
        for (int ks = 0; ks < 4; ++ks)
            bf[cc][ks] = *(const short8*)(WE2T + (size_t)col * 128 + ks * 32 + quad * 8);
    }

    int tmax = row_tiles - g * 8;              // block-uniform
    if (tmax > 8) tmax = 8;

    for (int t = 0; t < 8; ++t) {
        if (t >= tmax) break;                  // uniform: safe with barriers
        int r0 = (g * 8 + t) * 16;
        int arow = r0 + col16;
        if (arow >= N) arow = N - 1;

        // A-fragment: 4 loads feed 16 MFMAs
        short8 a[4];
        const unsigned short* ap = xb + (size_t)arow * 128 + quad * 8;
#pragma unroll
        for (int ks = 0; ks < 4; ++ks) a[ks] = *(const short8*)(ap + ks * 32);

        unsigned short* sbuf = st[t & 1];
#pragma unroll
        for (int cc = 0; cc < 4; ++cc) {
            f32x4 acc = {0.f, 0.f, 0.f, 0.f};
#pragma unroll
            for (int ks = 0; ks < 4; ++ks)
                acc = __builtin_amdgcn_mfma_f32_16x16x32_bf16(a[ks], bf[cc][ks], acc, 0, 0, 0);
#pragma unroll
            for (int r = 0; r < 4; ++r)
                sbuf[(quad * 4 + r) * 524 + wave * 64 + cc * 16 + col16] =
                    f2bf(acc[r] + bias[cc]);
        }

        __syncthreads();                       // one barrier per tile

        // store tile: 1024 us8-chunks, 512 threads x 2
#pragma unroll
        for (int p = 0; p < 2; ++p) {
            int chunk = tid + p * 512;
            int row = chunk >> 6;              // 0..15
            int cpos = (chunk & 63) * 8;       // 0..504
            if (r0 + row < N) {
                us8 v = *(const us8*)(sbuf + row * 524 + cpos);
                *(us8*)(T + (size_t)(r0 + row) * 512 + cpos) = v;
            }
        }
    }
}

// ---- Fused gather + tail: quarter-wave gather -> LDS -> MFMA --------------
__global__ __launch_bounds__(256, 2) void k_tailg(
    const unsigned short* __restrict__ T,    // [N][512] P|Q (read-only)
    const unsigned short* __restrict__ xb,   // [N][128]
    const int* __restrict__ deg,
    const int* __restrict__ adj,             // [N][32]
    const int* __restrict__ head,
    const unsigned long long* __restrict__ next2,
    const unsigned short* __restrict__ WnT,  // [256 c][128 k] col-major
    const unsigned short* __restrict__ WdT,  // [128 c][256 k] col-major
    const unsigned short* __restrict__ Wf1P, // [32 c][384 kp] permuted
    const float* __restrict__ b_node, const float* __restrict__ b_ed,
    const float* __restrict__ b_f1, const float* __restrict__ W_f2,
    const float* __restrict__ b_f2,
    float* __restrict__ out, int N, int row_tiles, int tiles_per_block)
{
    __shared__ unsigned short hslice[4][16 * 100];  // per-wave h (bf16)
    __shared__ float red[4][16][33];                // MLP partials
    __shared__ unsigned short xe[16 * 396];         // XA|EA per tile (pad 396)
    const int wave = threadIdx.x >> 6;
    const int lane = threadIdx.x & 63;
    const int quad = lane >> 4;
    const int col16 = lane & 15;

    // ---- persistent B fragments (loaded once per block) ----
    short8 bn[4][4], be[2][8], bfr[2][3];
    float bias_n[4], bias_e[2];
#pragma unroll
    for (int ci = 0; ci < 4; ++ci) {
        int col = (wave + ci * 4) * 16 + col16;
        bias_n[ci] = b_node[col];
#pragma unroll
        for (int ks = 0; ks < 4; ++ks)
            bn[ci][ks] = *(const short8*)(WnT + (size_t)col * 128 + ks * 32 + quad * 8);
    }
#pragma unroll
    for (int ci = 0; ci < 2; ++ci) {
        int col = (wave + ci * 4) * 16 + col16;
        bias_e[ci] = b_ed[col];
#pragma unroll
        for (int ks = 0; ks < 8; ++ks)
            be[ci][ks] = *(const short8*)(WdT + (size_t)col * 256 + ks * 32 + quad * 8);
    }
#pragma unroll
    for (int cc = 0; cc < 2; ++cc) {
        int c = cc * 16 + col16;
#pragma unroll
        for (int ks = 0; ks < 3; ++ks)
            bfr[cc][ks] = *(const short8*)(Wf1P + (size_t)c * 384 + wave * 96 + ks * 32 + quad * 8);
    }

    unsigned short* hw = &hslice[wave][0];
    int t0 = blockIdx.x * tiles_per_block;
    int t1 = t0 + tiles_per_block;
    if (t1 > row_tiles) t1 = row_tiles;

    for (int tile = t0; tile < t1; ++tile) {
        int r0 = tile * 16;

        // ================= gather phase: quarter-wave per node =============
        {
            int qn = wave * 4 + quad;            // node-in-tile 0..15
            int n = r0 + qn;
            bool act = n < N;
            int nn = act ? n : N - 1;
            int c = col16;

            // P row cols [c*16, c*16+16)
            us8 pv0 = *(const us8*)(T + (size_t)nn * 512 + c * 16);
            us8 pv1 = *(const us8*)(T + (size_t)nn * 512 + c * 16 + 8);
            float p[16];
#pragma unroll
            for (int j = 0; j < 8; ++j) { p[j] = bf2f(pv0[j]); p[j + 8] = bf2f(pv1[j]); }
            float aE[16];
#pragma unroll
            for (int j = 0; j < 16; ++j) aE[j] = 0.f;
            float aX[8] = {0, 0, 0, 0, 0, 0, 0, 0};

            int dg = act ? deg[n] : 0;
            int2 av = ((const int2*)(adj + (size_t)nn * 32))[c];  // slots 2c,2c+1
            int m = dg < 32 ? dg : 32;

            int k = 0;
            for (; k + 1 < m; k += 2) {          // 2-way unroll (validated R23)
                int s0 = __shfl(av.x, k >> 1, 16);
                int s1 = __shfl(av.y, k >> 1, 16);
                us8 q0a = *(const us8*)(T + (size_t)s0 * 512 + 256 + c * 16);
                us8 q0b = *(const us8*)(T + (size_t)s0 * 512 + 256 + c * 16 + 8);
                us8 q1a = *(const us8*)(T + (size_t)s1 * 512 + 256 + c * 16);
                us8 q1b = *(const us8*)(T + (size_t)s1 * 512 + 256 + c * 16 + 8);
                us8 x0 = *(const us8*)(xb + (size_t)s0 * 128 + c * 8);
                us8 x1 = *(const us8*)(xb + (size_t)s1 * 128 + c * 8);
#pragma unroll
                for (int j = 0; j < 8; ++j) {
                    aE[j]     += fmaxf(p[j] + bf2f(q0a[j]), 0.f);
                    aE[j + 8] += fmaxf(p[j + 8] + bf2f(q0b[j]), 0.f);
                    aE[j]     += fmaxf(p[j] + bf2f(q1a[j]), 0.f);
                    aE[j + 8] += fmaxf(p[j + 8] + bf2f(q1b[j]), 0.f);
                    aX[j] += bf2f(x0[j]) + bf2f(x1[j]);
                }
            }
            if (k < m) {                         // remainder (slot k is even)
                int s0 = __shfl((k & 1) ? av.y : av.x, k >> 1, 16);
                us8 q0a = *(const us8*)(T + (size_t)s0 * 512 + 256 + c * 16);
                us8 q0b = *(const us8*)(T + (size_t)s0 * 512 + 256 + c * 16 + 8);
                us8 x0 = *(const us8*)(xb + (size_t)s0 * 128 + c * 8);
#pragma unroll
                for (int j = 0; j < 8; ++j) {
                    aE[j]     += fmaxf(p[j] + bf2f(q0a[j]), 0.f);
                    aE[j + 8] += fmaxf(p[j + 8] + bf2f(q0b[j]), 0.f);
                    aX[j] += bf2f(x0[j]);
                }
            }

            // overflow fallback (deg > 32): residual linked list
            int cur = (act && dg > 32) ? head[n] : -1;
            while (__any(cur >= 0)) {
                bool v = cur >= 0;
                int safe = v ? cur : 0;
                unsigned long long e2 = next2[safe];
                int s = (int)(e2 >> 32);
                float mm = v ? 1.f : 0.f;
                us8 qa = *(const us8*)(T + (size_t)s * 512 + 256 + c * 16);
                us8 qb = *(const us8*)(T + (size_t)s * 512 + 256 + c * 16 + 8);
                us8 xv = *(const us8*)(xb + (size_t)s * 128 + c * 8);
#pragma unroll
                for (int j = 0; j < 8; ++j) {
                    aE[j]     += mm * fmaxf(p[j] + bf2f(qa[j]), 0.f);
                    aE[j + 8] += mm * fmaxf(p[j + 8] + bf2f(qb[j]), 0.f);
                    aX[j] += mm * bf2f(xv[j]);
                }
                cur = v ? (int)(unsigned)(e2 & 0xFFFFFFFFull) : -1;
            }

            // write to xe: row qn; XA cols [c*8,+8), EA cols 128+[c*16,+16)
            unsigned short* xr = xe + qn * 396;
            us8 xo;
#pragma unroll
            for (int j = 0; j < 8; ++j) xo[j] = f2bf(aX[j]);
            *(us8*)(xr + c * 8) = xo;
            us8 e0, e1;
#pragma unroll
            for (int j = 0; j < 8; ++j) { e0[j] = f2bf(aE[j]); e1[j] = f2bf(aE[j + 8]); }
            *(us8*)(xr + 128 + c * 16) = e0;
            *(us8*)(xr + 128 + c * 16 + 8) = e1;
        }
        __syncthreads();   // xe complete

        // ================= tail phase (A-fragments from xe) ================
        // --- node path: h[:,0:256], this wave's 4 chunks ---
        short8 ax[4];
#pragma unroll
        for (int ks = 0; ks < 4; ++ks)
            ax[ks] = *(const short8*)(xe + col16 * 396 + ks * 32 + quad * 8);
#pragma unroll
        for (int ci = 0; ci < 4; ++ci) {
            f32x4 acc = {0.f, 0.f, 0.f, 0.f};
#pragma unroll
            for (int ks = 0; ks < 4; ++ks)
                acc = __builtin_amdgcn_mfma_f32_16x16x32_bf16(ax[ks], bn[ci][ks], acc, 0, 0, 0);
#pragma unroll
            for (int r = 0; r < 4; ++r)
                hw[(quad * 4 + r) * 100 + ci * 16 + col16] =
                    f2bf(fmaxf(acc[r] + bias_n[ci], 0.f));
        }

        // --- edge path: h[:,256:384], this wave's 2 chunks ---
        short8 ae[8];
#pragma unroll
        for (int ks = 0; ks < 8; ++ks)
            ae[ks] = *(const short8*)(xe + col16 * 396 + 128 + ks * 32 + quad * 8);
#pragma unroll
        for (int ci = 0; ci < 2; ++ci) {
            f32x4 acc = {0.f, 0.f, 0.f, 0.f};
#pragma unroll
            for (int ks = 0; ks < 8; ++ks)
                acc = __builtin_amdgcn_mfma_f32_16x16x32_bf16(ae[ks], be[ci][ks], acc, 0, 0, 0);
#pragma unroll
            for (int r = 0; r < 4; ++r)
                hw[(quad * 4 + r) * 100 + 64 + ci * 16 + col16] =
                    f2bf(fmaxf(acc[r] + bias_e[ci], 0.f));
        }

        // --- MLP partial over own 96-K slice (same-wave LDS, no barrier) ---
        f32x4 m0 = {0.f, 0.f, 0.f, 0.f}, m1 = {0.f, 0.f, 0.f, 0.f};
#pragma unroll
        for (int ks = 0; ks < 3; ++ks) {
            short8 a = *(const short8*)(hw + col16 * 100 + ks * 32 + quad * 8);
            m0 = __builtin_amdgcn_mfma_f32_16x16x32_bf16(a, bfr[0][ks], m0, 0, 0, 0);
            m1 = __builtin_amdgcn_mfma_f32_16x16x32_bf16(a, bfr[1][ks], m1, 0, 0, 0);
        }
#pragma unroll
        for (int r = 0; r < 4; ++r) {
            red[wave][quad * 4 + r][col16] = m0[r];
            red[wave][quad * 4 + r][16 + col16] = m1[r];
        }
        __syncthreads();

        // --- final reduce + MLP2 + sigmoid on wave 0 ---
        if (wave == 0) {
            int row = col16, g = quad;          // each lane: 8 cols of one row
            float s = 0.f;
#pragma unroll
            for (int cc = 0; cc < 8; ++cc) {
                int col = g * 8 + cc;
                float v = red[0][row][col] + red[1][row][col] +
                          red[2][row][col] + red[3][row][col] + b_f1[col];
                s += fmaxf(v, 0.f) * W_f2[col];
            }
            s += __shfl_xor(s, 16, 64);
            s += __shfl_xor(s, 32, 64);
            if (g == 0 && r0 + row < N) {
                float v = s + b_f2[0];
                out[r0 + row] = 1.f / (1.f + __expf(-v));
            }
        }
        __syncthreads();   // red + xe reused next tile
    }
}

extern "C" void kernel_launch(void* const* d_in, const int* in_sizes, int n_in,
                              void* d_out, int out_size, void* d_ws, size_t ws_size,
                              hipStream_t stream) {
    const float* x      = (const float*)d_in[0];
    const int*   ei     = (const int*)d_in[1];
    // d_in[2] = e (unused)
    const float* W_node = (const float*)d_in[3];
    const float* b_node = (const float*)d_in[4];
    const float* W_edge = (const float*)d_in[5];
    const float* b_edge = (const float*)d_in[6];
    const float* W_ed   = (const float*)d_in[7];
    const float* b_ed   = (const float*)d_in[8];
    const float* W_f1   = (const float*)d_in[9];
    const float* b_f1   = (const float*)d_in[10];
    const float* W_f2   = (const float*)d_in[11];
    const float* b_f2   = (const float*)d_in[12];

    const int N = in_sizes[0] / 128;
    const int E = in_sizes[1] / 2;
    const int* src = ei;
    const int* dst = ei + E;

    char* ws = (char*)d_ws;
    size_t off = 0;
    auto alloc = [&](size_t bytes) { size_t o = off; off += (bytes + 255) & ~(size_t)255; return o; };
    unsigned short* xb   = (unsigned short*)(ws + alloc((size_t)N * 128 * 2));
    unsigned short* WE2T = (unsigned short*)(ws + alloc(512 * 128 * 2));
    unsigned short* WnT  = (unsigned short*)(ws + alloc(256 * 128 * 2));
    unsigned short* WdT  = (unsigned short*)(ws + alloc(128 * 256 * 2));
    unsigned short* Wf1P = (unsigned short*)(ws + alloc(32 * 384 * 2));
    unsigned short* T    = (unsigned short*)(ws + alloc((size_t)N * 512 * 2));
    int* head            = (int*)(ws + alloc((size_t)N * 4));
    unsigned long long* next2 = (unsigned long long*)(ws + alloc((size_t)E * 8));
    int* deg             = (int*)(ws + alloc((size_t)N * 4));
    int* adj             = (int*)(ws + alloc((size_t)N * 32 * 4));

    const int row_tiles   = (N + 15) / 16;
    const int row_groups  = (row_tiles + 7) / 8;
    const int quads       = N * 128 / 4;
    const int conv_items  = quads + 143360 + N;
    const int scat_blocks = (E + 511) / 512;
    const int gemm_blocks = row_groups;            // wide blocks: 1 per group
    int grid3 = scat_blocks * 3;
    int need_g = ((gemm_blocks + 1) / 2) * 3;
    if (need_g > grid3) grid3 = need_g;

    k_convert<<<(conv_items + 255) / 256, 256, 0, stream>>>(
        x, W_edge, W_node, W_ed, W_f1, xb, WE2T, WnT, WdT, Wf1P, head, deg,
        quads, N);
    k_sg<<<grid3, 512, 0, stream>>>(
        src, dst, head, next2, deg, adj, xb, WE2T, b_edge, T, E, N, row_tiles,
        scat_blocks, gemm_blocks);

    // 512 blocks: matches the ~2-block/CU register-pinned residency while
    // amortizing the per-block weight prologue over ~7 tiles (R24 lesson).
    int tail_blocks = 512;
    if (tail_blocks > row_tiles) tail_blocks = row_tiles;
    int tpb = (row_tiles + tail_blocks - 1) / tail_blocks;
    k_tailg<<<tail_blocks, 256, 0, stream>>>(
        T, xb, deg, adj, head, next2, WnT, WdT, Wf1P,
        b_node, b_ed, b_f1, W_f2, b_f2,
        (float*)d_out, N, row_tiles, tpb);
}